// Round 1
// baseline (205.622 us; speedup 1.0000x reference)
//
#include <hip/hip_runtime.h>

// ---------------------------------------------------------------------------
// CVXPolicy_DoubleIntegrator: fused MLP(193->100->100) + folded scatter GEMM
// (100->96) + per-row cubic Newton solve.
//
// ws layout (as int16 elements):
//   PW1 @ 0      : 7 kt * 14 frag * 512   (frag = [lane][8] bf16; f=nt*2+{hi,lo})
//   PW2 @ 50176  : 4 kt * 14 frag * 512
//   PW3q@ 78848  : 4 kt * 12 frag * 512
//   floats @ short-index 103424: pb1[112], pb2[112], pbq[96]
// Total 208128 bytes.
//
// MFMA 16x16x32 bf16 layouts (m89/m120-verified):
//   A: lane -> A[m = lane&15][k = (lane>>4)*8 + j]
//   B: lane -> B[k = (lane>>4)*8 + j][n = lane&15]
//   C/D: lane -> col = lane&15, row = (lane>>4)*4 + reg
// ---------------------------------------------------------------------------

typedef __attribute__((ext_vector_type(8))) short short8;
typedef __attribute__((ext_vector_type(4))) float f32x4;

__device__ __forceinline__ unsigned short f2bf(float f) {
  unsigned u = __float_as_uint(f);
  u += 0x7fffu + ((u >> 16) & 1u);           // RNE (finite values only)
  return (unsigned short)(u >> 16);
}
__device__ __forceinline__ float bf2f(unsigned short b) {
  return __uint_as_float(((unsigned)b) << 16);
}
__device__ __forceinline__ float tanh_fast(float x) {
  float ax = fabsf(x);
  float e = __builtin_amdgcn_exp2f(ax * -2.88539008177792681f);  // exp(-2ax)
  float r = (1.f - e) * __builtin_amdgcn_rcpf(1.f + e);
  return copysignf(r, x);
}

// ---------------------------------------------------------------------------
// Prep: pack weights into MFMA B-frag layout, bf16 hi/lo split, fold scatter.
// 52032 threads total.
// ---------------------------------------------------------------------------
__global__ void cvx_prep(const float* __restrict__ W1, const float* __restrict__ b1,
                         const float* __restrict__ W2, const float* __restrict__ b2,
                         const float* __restrict__ W3, const float* __restrict__ b3,
                         short* __restrict__ pw) {
  int idx = blockIdx.x * 256 + threadIdx.x;

  if (idx < 25088) {                       // L1: 7 kt * 7 nt * 512
    int kt = idx / 3584, rem = idx % 3584;
    int nt = rem / 512, e = rem % 512;
    int lane = e >> 3, j = e & 7;
    int k = kt * 32 + (lane >> 4) * 8 + j;   // x' = [z(0..191), t(192), pad]
    int n = nt * 16 + (lane & 15);
    float wv = 0.f;
    if (n < 100) {
      if (k < 192) wv = W1[(k + 1) * 100 + n];     // z_k  -> W1 row k+1
      else if (k == 192) wv = W1[n];               // t    -> W1 row 0
    }
    unsigned short hi = f2bf(wv);
    unsigned short lo = f2bf(wv - bf2f(hi));
    pw[(kt * 14 + nt * 2) * 512 + e] = (short)hi;
    pw[(kt * 14 + nt * 2 + 1) * 512 + e] = (short)lo;
    return;
  }
  idx -= 25088;
  if (idx < 14336) {                       // L2: 4 kt * 7 nt * 512
    int kt = idx / 3584, rem = idx % 3584;
    int nt = rem / 512, e = rem % 512;
    int lane = e >> 3, j = e & 7;
    int k = kt * 32 + (lane >> 4) * 8 + j;
    int n = nt * 16 + (lane & 15);
    float wv = (k < 100 && n < 100) ? W2[k * 100 + n] : 0.f;
    unsigned short hi = f2bf(wv);
    unsigned short lo = f2bf(wv - bf2f(hi));
    pw[50176 + (kt * 14 + nt * 2) * 512 + e] = (short)hi;
    pw[50176 + (kt * 14 + nt * 2 + 1) * 512 + e] = (short)lo;
    return;
  }
  idx -= 14336;
  if (idx < 12288) {                       // L3 folded: 4 kt * 6 nt * 512
    int kt = idx / 3072, rem = idx % 3072;
    int nt = rem / 512, e = rem % 512;
    int lane = e >> 3, j = e & 7;
    int k = kt * 32 + (lane >> 4) * 8 + j;
    int u = nt * 16 + (lane & 15);
    float wv = 0.f;
    if (k < 100) {
      const float* wr = W3 + k * 192;
      if (u <= 31) wv += wr[3 * u + 3];                    // set A: u=i
      if ((u & 1) == 0 && u <= 62) wv += wr[2 * u + 4];    // set B: u=2i
      if (u % 3 == 0 && u <= 93) wv += wr[(5 * u) / 3 + 5];// set C: u=3i
    }
    unsigned short hi = f2bf(wv);
    unsigned short lo = f2bf(wv - bf2f(hi));
    pw[78848 + (kt * 12 + nt * 2) * 512 + e] = (short)hi;
    pw[78848 + (kt * 12 + nt * 2 + 1) * 512 + e] = (short)lo;
    return;
  }
  idx -= 12288;
  float* pb = (float*)(pw + 103424);
  if (idx < 112) { pb[idx] = (idx < 100) ? b1[idx] : 0.f; return; }
  idx -= 112;
  if (idx < 112) { pb[112 + idx] = (idx < 100) ? b2[idx] : 0.f; return; }
  idx -= 112;
  if (idx < 96) {
    int u = idx;
    float v = 0.f;
    if (u <= 31) v += b3[3 * u + 3];
    if ((u & 1) == 0 && u <= 62) v += b3[2 * u + 4];
    if (u % 3 == 0 && u <= 93) v += b3[(5 * u) / 3 + 5];
    pb[224 + u] = v;
  }
}

// ---------------------------------------------------------------------------
// Main fused kernel. 128 rows/block, 4 waves, 32 rows/wave (wave-private).
// ---------------------------------------------------------------------------
__global__ __launch_bounds__(256, 2) void cvx_main(
    const float* __restrict__ zin, const float* __restrict__ tin,
    const short* __restrict__ pw, float* __restrict__ out) {
  __shared__ __align__(16) short wbuf[2][7168];   // 14 frags * 512 (double buf)
  __shared__ __align__(16) short hbuf[128 * 136]; // [row][col] bf16, pad to 136

  const int tid = threadIdx.x;
  const int wid = tid >> 6;
  const int lane = tid & 63;
  const int l15 = lane & 15;
  const int qd = lane >> 4;
  const int rb = blockIdx.x * 128 + wid * 32;   // wave's first global row
  const int lrb = wid * 32;                     // wave's first hbuf row

  const short* PW1 = pw;
  const short* PW2 = pw + 50176;
  const short* PW3 = pw + 78848;
  const float* pb1 = (const float*)(pw + 103424);
  const float* pb2 = pb1 + 112;
  const float* pbq = pb1 + 224;

  auto stage = [&](const short* src, int nf, int buf) {
    for (int f = wid; f < nf; f += 4) {
      const short* g = src + f * 512 + lane * 8;
      __builtin_amdgcn_global_load_lds(
          (const __attribute__((address_space(1))) void*)g,
          (__attribute__((address_space(3))) void*)&wbuf[buf][f * 512],
          16, 0, 0);
    }
  };
  stage(PW1, 14, 0);   // chunk 0 in flight ASAP

  // zero hbuf pad cols [112,128) for this wave's rows (read by kt=3 later)
  {
    int row = lrb + (lane >> 1);
    short8 zz = {0, 0, 0, 0, 0, 0, 0, 0};
    *(short8*)&hbuf[row * 136 + 112 + (lane & 1) * 8] = zz;
  }

  // ---- X A-fragments: x' = [z, t, pad], K = 224 (7 ktiles) ----
  short8 XA[2][7];
#pragma unroll
  for (int mt = 0; mt < 2; mt++) {
    const int row = rb + mt * 16 + l15;
    const float* zr = zin + (size_t)row * 192;
#pragma unroll
    for (int kt = 0; kt < 6; kt++) {
      const f32x4* p0 = (const f32x4*)(zr + kt * 32 + qd * 8);
      f32x4 v0 = p0[0], v1 = p0[1];
      short8 a;
      a[0] = (short)f2bf(v0[0]); a[1] = (short)f2bf(v0[1]);
      a[2] = (short)f2bf(v0[2]); a[3] = (short)f2bf(v0[3]);
      a[4] = (short)f2bf(v1[0]); a[5] = (short)f2bf(v1[1]);
      a[6] = (short)f2bf(v1[2]); a[7] = (short)f2bf(v1[3]);
      XA[mt][kt] = a;
    }
    short8 a7 = {0, 0, 0, 0, 0, 0, 0, 0};
    if (qd == 0) a7[0] = (short)f2bf(tin[row]);
    XA[mt][6] = a7;
  }

  // ---- Layer 1: [32,224] x [224,112] ----
  f32x4 acc[2][7];
#pragma unroll
  for (int nt = 0; nt < 7; nt++) {
    float bv = pb1[nt * 16 + l15];
    f32x4 bvv = {bv, bv, bv, bv};
    acc[0][nt] = bvv; acc[1][nt] = bvv;
  }
#pragma unroll
  for (int kt = 0; kt < 7; kt++) {
    __syncthreads();
    if (kt < 6) stage(PW1 + (kt + 1) * 7168, 14, (kt + 1) & 1);
    else        stage(PW2, 14, 1);                    // chunk 7
    const short* wb = wbuf[kt & 1];
#pragma unroll
    for (int nt = 0; nt < 7; nt++) {
      short8 bhi = *(const short8*)(wb + nt * 1024 + lane * 8);
      short8 blo = *(const short8*)(wb + nt * 1024 + 512 + lane * 8);
#pragma unroll
      for (int mt = 0; mt < 2; mt++) {
        acc[mt][nt] = __builtin_amdgcn_mfma_f32_16x16x32_bf16(XA[mt][kt], bhi, acc[mt][nt], 0, 0, 0);
        acc[mt][nt] = __builtin_amdgcn_mfma_f32_16x16x32_bf16(XA[mt][kt], blo, acc[mt][nt], 0, 0, 0);
      }
    }
  }
#pragma unroll
  for (int mt = 0; mt < 2; mt++)
#pragma unroll
    for (int nt = 0; nt < 7; nt++)
#pragma unroll
      for (int r = 0; r < 4; r++) {
        int row = lrb + mt * 16 + qd * 4 + r;
        hbuf[row * 136 + nt * 16 + l15] = (short)f2bf(tanh_fast(acc[mt][nt][r]));
      }

  // ---- Layer 2: [32,128] x [128,112] ----
  short8 HA[2][4];
#pragma unroll
  for (int mt = 0; mt < 2; mt++) {
    int row = lrb + mt * 16 + l15;
#pragma unroll
    for (int kt = 0; kt < 4; kt++)
      HA[mt][kt] = *(const short8*)&hbuf[row * 136 + kt * 32 + qd * 8];
  }
#pragma unroll
  for (int nt = 0; nt < 7; nt++) {
    float bv = pb2[nt * 16 + l15];
    f32x4 bvv = {bv, bv, bv, bv};
    acc[0][nt] = bvv; acc[1][nt] = bvv;
  }
#pragma unroll
  for (int kt = 0; kt < 4; kt++) {
    __syncthreads();
    if (kt < 3) stage(PW2 + (kt + 1) * 7168, 14, (8 + kt) & 1);
    else        stage(PW3, 12, 1);                    // chunk 11
    const short* wb = wbuf[(7 + kt) & 1];
#pragma unroll
    for (int nt = 0; nt < 7; nt++) {
      short8 bhi = *(const short8*)(wb + nt * 1024 + lane * 8);
      short8 blo = *(const short8*)(wb + nt * 1024 + 512 + lane * 8);
#pragma unroll
      for (int mt = 0; mt < 2; mt++) {
        acc[mt][nt] = __builtin_amdgcn_mfma_f32_16x16x32_bf16(HA[mt][kt], bhi, acc[mt][nt], 0, 0, 0);
        acc[mt][nt] = __builtin_amdgcn_mfma_f32_16x16x32_bf16(HA[mt][kt], blo, acc[mt][nt], 0, 0, 0);
      }
    }
  }
#pragma unroll
  for (int mt = 0; mt < 2; mt++)
#pragma unroll
    for (int nt = 0; nt < 7; nt++)
#pragma unroll
      for (int r = 0; r < 4; r++) {
        int row = lrb + mt * 16 + qd * 4 + r;
        hbuf[row * 136 + nt * 16 + l15] = (short)f2bf(tanh_fast(acc[mt][nt][r]));
      }

  // ---- Layer 3 (folded scatter): [32,128] x [128,96] -> q ----
#pragma unroll
  for (int mt = 0; mt < 2; mt++) {
    int row = lrb + mt * 16 + l15;
#pragma unroll
    for (int kt = 0; kt < 4; kt++)
      HA[mt][kt] = *(const short8*)&hbuf[row * 136 + kt * 32 + qd * 8];
  }
  f32x4 qacc[2][6];
#pragma unroll
  for (int nt = 0; nt < 6; nt++) {
    float bv = pbq[nt * 16 + l15];
    f32x4 bvv = {bv, bv, bv, bv};
    qacc[0][nt] = bvv; qacc[1][nt] = bvv;
  }
#pragma unroll
  for (int kt = 0; kt < 4; kt++) {
    __syncthreads();
    if (kt < 3) stage(PW3 + (kt + 1) * 6144, 12, (12 + kt) & 1);
    const short* wb = wbuf[(11 + kt) & 1];
#pragma unroll
    for (int nt = 0; nt < 6; nt++) {
      short8 bhi = *(const short8*)(wb + nt * 1024 + lane * 8);
      short8 blo = *(const short8*)(wb + nt * 1024 + 512 + lane * 8);
#pragma unroll
      for (int mt = 0; mt < 2; mt++) {
        qacc[mt][nt] = __builtin_amdgcn_mfma_f32_16x16x32_bf16(HA[mt][kt], bhi, qacc[mt][nt], 0, 0, 0);
        qacc[mt][nt] = __builtin_amdgcn_mfma_f32_16x16x32_bf16(HA[mt][kt], blo, qacc[mt][nt], 0, 0, 0);
      }
    }
  }

  // ---- QP epilogue: r = ||q||^2 per row, Newton s(1+s)^2 = r, u = -q/(1+s) ----
#pragma unroll
  for (int mt = 0; mt < 2; mt++) {
    f32x4 rs = {0.f, 0.f, 0.f, 0.f};
#pragma unroll
    for (int nt = 0; nt < 6; nt++) rs += qacc[mt][nt] * qacc[mt][nt];
    // quad-wide (16-lane) reduction; every lane ends with all 4 row-sums
    float rv[4];
#pragma unroll
    for (int r = 0; r < 4; r++) {
      float v = rs[r];
      v += __shfl_xor(v, 1);
      v += __shfl_xor(v, 2);
      v += __shfl_xor(v, 4);
      v += __shfl_xor(v, 8);
      rv[r] = v;
    }
    // Newton distributed: this lane solves row r = l15&3, broadcast back
    float r2 = rv[l15 & 3];
    float s = __builtin_amdgcn_exp2f(__builtin_amdgcn_logf(r2) * 0.333333333333f);
#pragma unroll
    for (int it = 0; it < 8; it++) {
      float one = 1.f + s;
      float fv = fmaf(s * one, one, -r2);
      float fp = one * fmaf(2.f, s, one);
      s = fmaxf(s - fv * __builtin_amdgcn_rcpf(fp), 0.f);
    }
    float myinv = -__builtin_amdgcn_rcpf(1.f + s);
#pragma unroll
    for (int r = 0; r < 4; r++) {
      float inv = __shfl(myinv, (lane & 48) | r);
      int row = rb + mt * 16 + qd * 4 + r;
      float* orow = out + (size_t)row * 96;
#pragma unroll
      for (int nt = 0; nt < 6; nt++)
        orow[nt * 16 + l15] = qacc[mt][nt][r] * inv;
    }
  }
}

extern "C" void kernel_launch(void* const* d_in, const int* in_sizes, int n_in,
                              void* d_out, int out_size, void* d_ws, size_t ws_size,
                              hipStream_t stream) {
  const float* z  = (const float*)d_in[0];
  const float* t  = (const float*)d_in[1];
  const float* W1 = (const float*)d_in[2];
  const float* b1 = (const float*)d_in[3];
  const float* W2 = (const float*)d_in[4];
  const float* b2 = (const float*)d_in[5];
  const float* W3 = (const float*)d_in[6];
  const float* b3 = (const float*)d_in[7];
  float* out = (float*)d_out;
  int B = in_sizes[0] / 192;                 // 131072

  short* pw = (short*)d_ws;                  // needs 208128 bytes
  cvx_prep<<<204, 256, 0, stream>>>(W1, b1, W2, b2, W3, b3, pw);
  cvx_main<<<B / 128, 256, 0, stream>>>(z, t, pw, out);
}

// Round 2
// 192.781 us; speedup vs baseline: 1.0666x; 1.0666x over previous
//
#include <hip/hip_runtime.h>
#include <hip/hip_bf16.h>

// ---------------------------------------------------------------------------
// CVXPolicy_DoubleIntegrator, R2: weights-resident-in-LDS, barrier-free.
//
// Packed weights (bf16, scatter folded into W3, t-row of W1 removed):
//   PW1: frag (kt*7+nt), kt<6, nt<7        -> shorts [0, 21504)
//   PW2: frag 42+kt*7+nt, kt<4, nt<7       -> shorts [21504, 35840)
//   PW3: frag 70+kt*6+nt, kt<4, nt<6       -> shorts [35840, 48128)
//   floats at short-index 48128: w0[112], b1[112], b2[112], bq[96]
// frag = 512 shorts: element e = lane*8+j -> B[k = kt*32+(lane>>4)*8+j][n = nt*16+(lane&15)]
//
// MFMA 16x16x32 bf16 layouts (verified in R1, passed):
//   A:   lane -> A[m = lane&15][k = (lane>>4)*8 + j]
//   C/D: lane -> col = lane&15, row = (lane>>4)*4 + reg
//
// Main kernel: 512 thr (8 waves), 1 block/CU (grid 256), 2 tiles x 256 rows.
// Weights staged to LDS once; ONE __syncthreads total; waves independent.
// ---------------------------------------------------------------------------

typedef __attribute__((ext_vector_type(8))) short short8;
typedef __attribute__((ext_vector_type(4))) short short4v;
typedef __attribute__((ext_vector_type(4))) float f32x4;

#define HST 116  // hbuf row stride in shorts (232B: 8B-aligned, uniform banks)

__device__ __forceinline__ unsigned short f2bf(float f) {
  unsigned u = __float_as_uint(f);
  u += 0x7fffu + ((u >> 16) & 1u);  // RNE (finite values only)
  return (unsigned short)(u >> 16);
}
__device__ __forceinline__ float tanh_fast(float x) {
  float ax = fabsf(x);
  float e = __builtin_amdgcn_exp2f(ax * -2.88539008177792681f);  // exp(-2ax)
  float r = (1.f - e) * __builtin_amdgcn_rcpf(1.f + e);
  return copysignf(r, x);
}

// ---------------------------------------------------------------------------
// Prep: pack weights bf16, fold scatter into W3, drop t-row (kept as w0 f32).
// ---------------------------------------------------------------------------
__global__ void cvx_prep(const float* __restrict__ W1, const float* __restrict__ b1,
                         const float* __restrict__ W2, const float* __restrict__ b2,
                         const float* __restrict__ W3, const float* __restrict__ b3,
                         short* __restrict__ pw) {
  int idx = blockIdx.x * 256 + threadIdx.x;

  if (idx < 21504) {                        // PW1: 6 kt * 7 nt * 512
    int kt = idx / 3584, rem = idx % 3584;
    int nt = rem / 512, e = rem % 512;
    int lane = e >> 3, j = e & 7;
    int k = kt * 32 + (lane >> 4) * 8 + j;  // z index; W1 row k+1
    int n = nt * 16 + (lane & 15);
    float wv = (n < 100) ? W1[(k + 1) * 100 + n] : 0.f;
    pw[(kt * 7 + nt) * 512 + e] = (short)f2bf(wv);
    return;
  }
  idx -= 21504;
  if (idx < 14336) {                        // PW2: 4 kt * 7 nt * 512
    int kt = idx / 3584, rem = idx % 3584;
    int nt = rem / 512, e = rem % 512;
    int lane = e >> 3, j = e & 7;
    int k = kt * 32 + (lane >> 4) * 8 + j;
    int n = nt * 16 + (lane & 15);
    float wv = (k < 100 && n < 100) ? W2[k * 100 + n] : 0.f;
    pw[21504 + (kt * 7 + nt) * 512 + e] = (short)f2bf(wv);
    return;
  }
  idx -= 14336;
  if (idx < 12288) {                        // PW3 folded: 4 kt * 6 nt * 512
    int kt = idx / 3072, rem = idx % 3072;
    int nt = rem / 512, e = rem % 512;
    int lane = e >> 3, j = e & 7;
    int k = kt * 32 + (lane >> 4) * 8 + j;
    int u = nt * 16 + (lane & 15);          // u < 96
    float wv = 0.f;
    if (k < 100) {
      const float* wr = W3 + k * 192;
      if (u <= 31) wv += wr[3 * u + 3];                     // u = i
      if ((u & 1) == 0 && u <= 62) wv += wr[2 * u + 4];     // u = 2i
      if (u % 3 == 0 && u <= 93) wv += wr[(5 * u) / 3 + 5]; // u = 3i
    }
    pw[35840 + (kt * 6 + nt) * 512 + e] = (short)f2bf(wv);
    return;
  }
  idx -= 12288;
  float* cb = (float*)(pw + 48128);
  if (idx < 112) { cb[idx] = (idx < 100) ? W1[idx] : 0.f; return; }        // w0 = W1 row 0
  idx -= 112;
  if (idx < 112) { cb[112 + idx] = (idx < 100) ? b1[idx] : 0.f; return; }
  idx -= 112;
  if (idx < 112) { cb[224 + idx] = (idx < 100) ? b2[idx] : 0.f; return; }
  idx -= 112;
  if (idx < 96) {
    int u = idx;
    float v = 0.f;
    if (u <= 31) v += b3[3 * u + 3];
    if ((u & 1) == 0 && u <= 62) v += b3[2 * u + 4];
    if (u % 3 == 0 && u <= 93) v += b3[(5 * u) / 3 + 5];
    cb[336 + u] = v;
  }
}

// ---------------------------------------------------------------------------
// Main fused kernel.
// ---------------------------------------------------------------------------
__global__ __launch_bounds__(512, 2) void cvx_main(
    const float* __restrict__ zin, const float* __restrict__ tin,
    const short* __restrict__ pw, float* __restrict__ out) {
  __shared__ __align__(16) short wbuf[48128];        // 96,256 B: all weights
  __shared__ __align__(16) short hbuf[8 * 32 * HST]; // 59,392 B: per-wave h

  const int tid = threadIdx.x;
  const int wid = tid >> 6;
  const int lane = tid & 63;
  const int l15 = lane & 15;
  const int qd = lane >> 4;

  // stage ALL weights into LDS (once per block)
  for (int f = wid; f < 94; f += 8) {
    const short* g = pw + f * 512 + lane * 8;
    __builtin_amdgcn_global_load_lds(
        (const __attribute__((address_space(1))) void*)g,
        (__attribute__((address_space(3))) void*)&wbuf[f * 512], 16, 0, 0);
  }

  // biases / w0 into registers (constant across tiles)
  const float* cb = (const float*)(pw + 48128);
  float w0v[7], b1v[7], b2v[7], bqv[6];
#pragma unroll
  for (int nt = 0; nt < 7; nt++) {
    w0v[nt] = cb[nt * 16 + l15];
    b1v[nt] = cb[112 + nt * 16 + l15];
    b2v[nt] = cb[224 + nt * 16 + l15];
  }
#pragma unroll
  for (int nt = 0; nt < 6; nt++) bqv[nt] = cb[336 + nt * 16 + l15];

  const int row0 = blockIdx.x * 512 + wid * 32;
  const int hb = wid * 32 * HST;

  // prefetch tile 0 z,t into registers (overlaps weight staging)
  f32x4 zc[2][6][2];
  float tc[2];
#pragma unroll
  for (int mt = 0; mt < 2; mt++) {
    const float* zr = zin + (size_t)(row0 + mt * 16 + l15) * 192 + qd * 8;
#pragma unroll
    for (int kt = 0; kt < 6; kt++) {
      zc[mt][kt][0] = *(const f32x4*)(zr + kt * 32);
      zc[mt][kt][1] = *(const f32x4*)(zr + kt * 32 + 4);
    }
    tc[mt] = tin[row0 + mt * 16 + l15];
  }

  __syncthreads();  // the only barrier: weights resident from here on

  auto ldh = [&](int off) -> short8 {   // 8B-aligned LDS read of 8 shorts
    short4v a = *(const short4v*)&hbuf[off];
    short4v b = *(const short4v*)&hbuf[off + 4];
    return __builtin_shufflevector(a, b, 0, 1, 2, 3, 4, 5, 6, 7);
  };

#pragma unroll 1
  for (int it = 0; it < 2; ++it) {
    const int rb = row0 + it * 256;

    // ---- build A fragments from prefetched z ----
    short8 XA[2][6];
#pragma unroll
    for (int mt = 0; mt < 2; mt++)
#pragma unroll
      for (int kt = 0; kt < 6; kt++) {
        union { short8 s; __hip_bfloat162 h[4]; } u;
        f32x4 a = zc[mt][kt][0], b = zc[mt][kt][1];
        u.h[0] = __float22bfloat162_rn(make_float2(a[0], a[1]));
        u.h[1] = __float22bfloat162_rn(make_float2(a[2], a[3]));
        u.h[2] = __float22bfloat162_rn(make_float2(b[0], b[1]));
        u.h[3] = __float22bfloat162_rn(make_float2(b[2], b[3]));
        XA[mt][kt] = u.s;
      }
    float tv0 = tc[0], tv1 = tc[1];

    // ---- prefetch next tile while this one computes ----
    if (it == 0) {
#pragma unroll
      for (int mt = 0; mt < 2; mt++) {
        const float* zr = zin + (size_t)(row0 + 256 + mt * 16 + l15) * 192 + qd * 8;
#pragma unroll
        for (int kt = 0; kt < 6; kt++) {
          zc[mt][kt][0] = *(const f32x4*)(zr + kt * 32);
          zc[mt][kt][1] = *(const f32x4*)(zr + kt * 32 + 4);
        }
        tc[mt] = tin[row0 + 256 + mt * 16 + l15];
      }
    }

    // ---- Layer 1: [32,192] x [192,112] ----
    f32x4 acc[2][7];
#pragma unroll
    for (int nt = 0; nt < 7; nt++) {
      f32x4 zzz = {0.f, 0.f, 0.f, 0.f};
      acc[0][nt] = zzz; acc[1][nt] = zzz;
    }
#pragma unroll
    for (int kt = 0; kt < 6; kt++)
#pragma unroll
      for (int nt = 0; nt < 7; nt++) {
        short8 bf = *(const short8*)&wbuf[(kt * 7 + nt) * 512 + lane * 8];
        acc[0][nt] = __builtin_amdgcn_mfma_f32_16x16x32_bf16(XA[0][kt], bf, acc[0][nt], 0, 0, 0);
        acc[1][nt] = __builtin_amdgcn_mfma_f32_16x16x32_bf16(XA[1][kt], bf, acc[1][nt], 0, 0, 0);
      }
    // t rank-1 fixup + bias + tanh -> hbuf
    float tr[2][4];
#pragma unroll
    for (int r = 0; r < 4; r++) {
      tr[0][r] = __shfl(tv0, qd * 4 + r);
      tr[1][r] = __shfl(tv1, qd * 4 + r);
    }
#pragma unroll
    for (int mt = 0; mt < 2; mt++)
#pragma unroll
      for (int nt = 0; nt < 7; nt++)
#pragma unroll
        for (int r = 0; r < 4; r++) {
          float v = fmaf(tr[mt][r], w0v[nt], acc[mt][nt][r] + b1v[nt]);
          hbuf[hb + (mt * 16 + qd * 4 + r) * HST + nt * 16 + l15] = (short)f2bf(tanh_fast(v));
        }

    // ---- Layer 2: [32,128] x [128,112] (kt=3: K rows 112..127 are B-zero) ----
    short8 HA[2][4];
#pragma unroll
    for (int mt = 0; mt < 2; mt++) {
      int ro = hb + (mt * 16 + l15) * HST;
#pragma unroll
      for (int kt = 0; kt < 3; kt++) HA[mt][kt] = ldh(ro + kt * 32 + qd * 8);
      HA[mt][3] = ldh(ro + 96 + (qd & 1) * 8);  // qd>=2 garbage x B-zero = 0
    }
#pragma unroll
    for (int nt = 0; nt < 7; nt++) {
      f32x4 zzz = {0.f, 0.f, 0.f, 0.f};
      acc[0][nt] = zzz; acc[1][nt] = zzz;
    }
#pragma unroll
    for (int kt = 0; kt < 4; kt++)
#pragma unroll
      for (int nt = 0; nt < 7; nt++) {
        short8 bf = *(const short8*)&wbuf[(42 + kt * 7 + nt) * 512 + lane * 8];
        acc[0][nt] = __builtin_amdgcn_mfma_f32_16x16x32_bf16(HA[0][kt], bf, acc[0][nt], 0, 0, 0);
        acc[1][nt] = __builtin_amdgcn_mfma_f32_16x16x32_bf16(HA[1][kt], bf, acc[1][nt], 0, 0, 0);
      }
#pragma unroll
    for (int mt = 0; mt < 2; mt++)
#pragma unroll
      for (int nt = 0; nt < 7; nt++)
#pragma unroll
        for (int r = 0; r < 4; r++) {
          float v = acc[mt][nt][r] + b2v[nt];
          hbuf[hb + (mt * 16 + qd * 4 + r) * HST + nt * 16 + l15] = (short)f2bf(tanh_fast(v));
        }

    // ---- Layer 3 (scatter-folded): [32,128] x [128,96] -> q ----
#pragma unroll
    for (int mt = 0; mt < 2; mt++) {
      int ro = hb + (mt * 16 + l15) * HST;
#pragma unroll
      for (int kt = 0; kt < 3; kt++) HA[mt][kt] = ldh(ro + kt * 32 + qd * 8);
      HA[mt][3] = ldh(ro + 96 + (qd & 1) * 8);
    }
    f32x4 qa[2][6];
#pragma unroll
    for (int nt = 0; nt < 6; nt++) {
      f32x4 zzz = {0.f, 0.f, 0.f, 0.f};
      qa[0][nt] = zzz; qa[1][nt] = zzz;
    }
#pragma unroll
    for (int kt = 0; kt < 4; kt++)
#pragma unroll
      for (int nt = 0; nt < 6; nt++) {
        short8 bf = *(const short8*)&wbuf[(70 + kt * 6 + nt) * 512 + lane * 8];
        qa[0][nt] = __builtin_amdgcn_mfma_f32_16x16x32_bf16(HA[0][kt], bf, qa[0][nt], 0, 0, 0);
        qa[1][nt] = __builtin_amdgcn_mfma_f32_16x16x32_bf16(HA[1][kt], bf, qa[1][nt], 0, 0, 0);
      }

    // ---- QP epilogue ----
#pragma unroll
    for (int mt = 0; mt < 2; mt++) {
#pragma unroll
      for (int nt = 0; nt < 6; nt++) {
        float bq = bqv[nt];
        qa[mt][nt][0] += bq; qa[mt][nt][1] += bq;
        qa[mt][nt][2] += bq; qa[mt][nt][3] += bq;
      }
      f32x4 rs = {0.f, 0.f, 0.f, 0.f};
#pragma unroll
      for (int nt = 0; nt < 6; nt++) rs += qa[mt][nt] * qa[mt][nt];
      float rv[4];
#pragma unroll
      for (int r = 0; r < 4; r++) {
        float v = rs[r];
        v += __shfl_xor(v, 1);
        v += __shfl_xor(v, 2);
        v += __shfl_xor(v, 4);
        v += __shfl_xor(v, 8);
        rv[r] = v;
      }
      float r2 = rv[l15 & 3];
      float s = __builtin_amdgcn_exp2f(__builtin_amdgcn_logf(r2) * 0.333333333333f);
#pragma unroll
      for (int itn = 0; itn < 8; itn++) {
        float one = 1.f + s;
        float fv = fmaf(s * one, one, -r2);
        float fp = one * fmaf(2.f, s, one);
        s = fmaxf(s - fv * __builtin_amdgcn_rcpf(fp), 0.f);
      }
      float myinv = -__builtin_amdgcn_rcpf(1.f + s);
#pragma unroll
      for (int r = 0; r < 4; r++) {
        float inv = __shfl(myinv, (lane & 48) | r);
        float* orow = out + (size_t)(rb + mt * 16 + qd * 4 + r) * 96;
#pragma unroll
        for (int nt = 0; nt < 6; nt++)
          orow[nt * 16 + l15] = qa[mt][nt][r] * inv;
      }
    }
  }
}

extern "C" void kernel_launch(void* const* d_in, const int* in_sizes, int n_in,
                              void* d_out, int out_size, void* d_ws, size_t ws_size,
                              hipStream_t stream) {
  const float* z  = (const float*)d_in[0];
  const float* t  = (const float*)d_in[1];
  const float* W1 = (const float*)d_in[2];
  const float* b1 = (const float*)d_in[3];
  const float* W2 = (const float*)d_in[4];
  const float* b2 = (const float*)d_in[5];
  const float* W3 = (const float*)d_in[6];
  const float* b3 = (const float*)d_in[7];
  float* out = (float*)d_out;
  int B = in_sizes[0] / 192;                 // 131072

  short* pw = (short*)d_ws;                  // 97,984 bytes used
  cvx_prep<<<190, 256, 0, stream>>>(W1, b1, W2, b2, W3, b3, pw);
  cvx_main<<<B / 512, 512, 0, stream>>>(z, t, pw, out);
}